// Round 7
// baseline (211.023 us; speedup 1.0000x reference)
//
#include <hip/hip_runtime.h>
#include <math.h>

#define NN 20000   // nodes
#define NE 40000   // edges
#define H 64
#define F_ATOM 62
#define F_BOND 6
#define NB 512     // graphs

typedef __bf16 bf16x8 __attribute__((ext_vector_type(8)));
typedef float f32x16 __attribute__((ext_vector_type(16)));

__device__ __forceinline__ float selu_f(float x) {
    const float scale = 1.0507009873554805f;
    const float alpha = 1.6732632423543772f;
    return scale * (x > 0.0f ? x : alpha * (__expf(x) - 1.0f));
}

// Fused prep, role by blockIdx (256 threads each):
// [0,625)      : mlpT[i][e] = relu(ef[e]@Wm+bm), transposed via LDS tile (64 edges/block)
// [625,5625)   : h = pad(nf)
// [5625,5753)  : ewb = bf16(Ew) in B-fragment-linear order   (round-3 verbatim math, PASSED)
// [5753,7003)  : zero msg (float4)
// [7003,7035)  : zero gsum (float4)
__global__ void prep_kernel(const float* __restrict__ nf, const float* __restrict__ ef,
                            const float* __restrict__ Wm, const float* __restrict__ bm,
                            const float* __restrict__ Ew,
                            float* __restrict__ h, float* __restrict__ mlpT,
                            __bf16* __restrict__ ewb, float* __restrict__ msg,
                            float* __restrict__ gsum) {
    const int bid = blockIdx.x;
    const int t = threadIdx.x;
    if (bid < 625) {
        __shared__ float st[64][65];
        const int el = t & 63;
        const int ig = t >> 6;                 // 0..3 (wave id); i = ig*16+p is wave-uniform
        const int e = bid * 64 + el;
        const float* efe = ef + e * F_BOND;
        const float e0 = efe[0], e1 = efe[1], e2 = efe[2];
        const float e3 = efe[3], e4 = efe[4], e5 = efe[5];
#pragma unroll
        for (int p = 0; p < 16; ++p) {
            const int i = ig * 16 + p;
            float s = bm[i];
            s = fmaf(e0, Wm[0 * H + i], s);
            s = fmaf(e1, Wm[1 * H + i], s);
            s = fmaf(e2, Wm[2 * H + i], s);
            s = fmaf(e3, Wm[3 * H + i], s);
            s = fmaf(e4, Wm[4 * H + i], s);
            s = fmaf(e5, Wm[5 * H + i], s);
            st[i][el] = fmaxf(s, 0.0f);
        }
        __syncthreads();
        const int ro = t >> 2;                 // output row i = 0..63
        const int ch = t & 3;                  // 16-edge chunk
#pragma unroll
        for (int k4 = 0; k4 < 4; ++k4) {
            float4 v;
            v.x = st[ro][ch * 16 + k4 * 4 + 0];
            v.y = st[ro][ch * 16 + k4 * 4 + 1];
            v.z = st[ro][ch * 16 + k4 * 4 + 2];
            v.w = st[ro][ch * 16 + k4 * 4 + 3];
            *reinterpret_cast<float4*>(mlpT + (size_t)ro * NE + bid * 64 + ch * 16 + k4 * 4) = v;
        }
    } else if (bid < 5625) {
        int idx = (bid - 625) * 256 + t;
        int n = idx >> 6, c = idx & 63;
        h[idx] = (c < F_ATOM) ? nf[n * F_ATOM + c] : 0.0f;
    } else if (bid < 5753) {
        int tid = (bid - 5625) * 256 + t;      // 0..32767
        int l = tid & 63;
        int nt = (tid >> 6) & 1;
        int c = tid >> 7;                      // 0..255 = kk*4 + q
        int kk = c >> 2;
        int jbase = (c & 3) * 16 + (l >> 5) * 8;
        int i = nt * 32 + (l & 31);
        const float* src = Ew + kk * 4096 + i * 64 + jbase;
        __bf16* dst = ewb + tid * 8;
#pragma unroll
        for (int q = 0; q < 8; ++q) dst[q] = (__bf16)src[q];
    } else if (bid < 7003) {
        int idx = (bid - 5753) * 256 + t;
        reinterpret_cast<float4*>(msg)[idx] = make_float4(0.f, 0.f, 0.f, 0.f);
    } else {
        int idx = (bid - 7003) * 256 + t;
        reinterpret_cast<float4*>(gsum)[idx] = make_float4(0.f, 0.f, 0.f, 0.f);
    }
}

// em[e,i] = sum_{kk,j} mlp[e,kk]*hj[e,j]*Ew[kk,i*64+j]; atomicAdd into msg[ed[e]]
// Block: 256 threads = 4 waves, 128 edges (wave w owns edges [eb+w*32, +32)), FULL K.
// B (ewb) streams L2 -> registers, double-buffered 1-kk ahead. NO LDS in hot loop,
// no waitcnt barriers; rendezvous s_barrier every 8 kk keeps waves L1-lockstep.
// A-build / B byte-layout / C/D scatter: round-2/5-verbatim math (PASSED, 9.8e-4).
__global__ __launch_bounds__(256) void edge_message_mfma(
    const float* __restrict__ h, const float* __restrict__ mlpT,
    const int* __restrict__ ed, const int* __restrict__ er,
    const __bf16* __restrict__ ewb, float* __restrict__ msg)
{
    __shared__ int edom_s[128];
    const int t = threadIdx.x;
    const int w = t >> 6;                 // 0..3
    const int lane = t & 63;
    const int l31 = lane & 31;
    const int hf = lane >> 5;
    const int eb = blockIdx.x * 128;

    if (t < 128) {
        int ee = eb + t;
        edom_s[t] = ed[ee < NE ? ee : NE - 1];
    }
    __syncthreads();

    const int eA = eb + w * 32 + l31;
    const int eAc = eA < NE ? eA : NE - 1;
    const int gA = er[eAc];

    // per-lane hj: j = q*16 + hf*8 + tt   (round-2 verbatim)
    float hjr[32];
    {
        const float* hp = h + gA * H + hf * 8;
#pragma unroll
        for (int q = 0; q < 4; ++q) {
            float4 v0 = *reinterpret_cast<const float4*>(hp + q * 16);
            float4 v1 = *reinterpret_cast<const float4*>(hp + q * 16 + 4);
            hjr[q * 8 + 0] = v0.x; hjr[q * 8 + 1] = v0.y;
            hjr[q * 8 + 2] = v0.z; hjr[q * 8 + 3] = v0.w;
            hjr[q * 8 + 4] = v1.x; hjr[q * 8 + 5] = v1.y;
            hjr[q * 8 + 6] = v1.z; hjr[q * 8 + 7] = v1.w;
        }
    }

    // B fragment bytes for (kk, q, nt): kk*8192 + (q*2+nt)*1024 + lane*16  (proven layout)
    const char* bp = reinterpret_cast<const char*>(ewb) + lane * 16;
    const float* mp = mlpT + eAc;         // + kk*NE per kk (coalesced dword across lanes)

    f32x16 acc0, acc1;
#pragma unroll
    for (int i = 0; i < 16; ++i) { acc0[i] = 0.0f; acc1[i] = 0.0f; }

    bf16x8 bA[8], bB[8];
    float mvA, mvB;

    auto LOADB = [&](bf16x8* bf, int kk) {
#pragma unroll
        for (int f = 0; f < 8; ++f)
            bf[f] = *reinterpret_cast<const bf16x8*>(bp + (size_t)kk * 8192 + f * 1024);
    };
    auto COMP = [&](const bf16x8* bf, float mv) {
#pragma unroll
        for (int q = 0; q < 4; ++q) {
            bf16x8 a;
#pragma unroll
            for (int tt = 0; tt < 8; ++tt) a[tt] = (__bf16)(mv * hjr[q * 8 + tt]);
            acc0 = __builtin_amdgcn_mfma_f32_32x32x16_bf16(a, bf[q * 2 + 0], acc0, 0, 0, 0);
            acc1 = __builtin_amdgcn_mfma_f32_32x32x16_bf16(a, bf[q * 2 + 1], acc1, 0, 0, 0);
        }
    };

    LOADB(bA, 0);
    mvA = mp[0];

#pragma unroll
    for (int g = 0; g < 8; ++g) {
#pragma unroll
        for (int p = 0; p < 4; ++p) {
            const int kk = g * 8 + p * 2;
            LOADB(bB, kk + 1);
            mvB = mp[(size_t)(kk + 1) * NE];
            COMP(bA, mvA);
            if (kk + 2 < 64) {
                LOADB(bA, kk + 2);
                mvA = mp[(size_t)(kk + 2) * NE];
            }
            COMP(bB, mvB);
        }
        if (g < 7) __builtin_amdgcn_s_barrier();   // rendezvous only: keep waves L1-lockstep
    }

    // C/D layout: col = lane&31, row = (r&3) + 8*(r>>2) + 4*(lane>>5)   (round-2 verbatim)
#pragma unroll
    for (int r = 0; r < 16; ++r) {
        const int m = (r & 3) + 8 * (r >> 2) + 4 * hf;
        const int em = eb + w * 32 + m;
        if (em < NE) {
            const int dom = edom_s[w * 32 + m];
            atomicAdd(&msg[dom * H + l31], acc0[r]);
            atomicAdd(&msg[dom * H + 32 + l31], acc1[r]);
        }
    }
}

// h[n,i] = selu(msg[n] @ Wu + bu[i] + h[n,i]); zeroes msg after read (round-3 verbatim)
__global__ void node_update_kernel(float* __restrict__ msg, const float* __restrict__ Wu,
                                   const float* __restrict__ bu, float* __restrict__ h) {
    __shared__ float ms[4][68];
    int t = threadIdx.x;
    int nb = blockIdx.x * 4;
    int ln = t >> 6, i = t & 63;
    int o = (nb + ln) * H + i;
    ms[ln][i] = msg[o];
    msg[o] = 0.0f;                       // ready for next edge_message / replay
    __syncthreads();
    float s = bu[i];
#pragma unroll
    for (int k = 0; k < H; ++k) s = fmaf(ms[ln][k], Wu[k * H + i], s);
    h[o] = selu_f(s + h[o]);
}

// fused: ae = h@Wae+bae; aa = selu(ae@WR+bR); atomicAdd gsum[gid[n]]   (round-3 verbatim)
__global__ void embed_readout_kernel(const float* __restrict__ h, const float* __restrict__ Wae,
                                     const float* __restrict__ bae, const float* __restrict__ WR,
                                     const float* __restrict__ bR, const int* __restrict__ gid,
                                     float* __restrict__ gsum) {
    __shared__ float hs[4][68];
    __shared__ float as_[4][68];
    int t = threadIdx.x;
    int nb = blockIdx.x * 4;
    int ln = t >> 6, i = t & 63;
    hs[ln][i] = h[(nb + ln) * H + i];
    __syncthreads();
    float s = bae[i];
#pragma unroll
    for (int k = 0; k < H; ++k) s = fmaf(hs[ln][k], Wae[k * H + i], s);
    as_[ln][i] = s;
    __syncthreads();
    float s2 = bR[i];
#pragma unroll
    for (int k = 0; k < H; ++k) s2 = fmaf(as_[ln][k], WR[k * H + i], s2);
    atomicAdd(&gsum[gid[nb + ln] * H + i], selu_f(s2));
}

// per graph: ge = tanh(gsum); mo = relu(ge @ Wmlp + bmlp); out = mo @ Wout + bout (round-1 verbatim)
__global__ void final_kernel(const float* __restrict__ gsum, const float* __restrict__ Wmlp,
                             const float* __restrict__ bmlp, const float* __restrict__ Wout,
                             const float* __restrict__ bout, float* __restrict__ out) {
    __shared__ float ge[64];
    int g = blockIdx.x, i = threadIdx.x;
    ge[i] = tanhf(gsum[g * H + i]);
    __syncthreads();
    float s = bmlp[i];
#pragma unroll
    for (int k = 0; k < H; ++k) s = fmaf(ge[k], Wmlp[k * H + i], s);
    float mo = fmaxf(s, 0.0f) * Wout[i];
#pragma unroll
    for (int off = 32; off > 0; off >>= 1) mo += __shfl_down(mo, off);
    if (i == 0) out[g] = mo + bout[0];
}

extern "C" void kernel_launch(void* const* d_in, const int* in_sizes, int n_in,
                              void* d_out, int out_size, void* d_ws, size_t ws_size,
                              hipStream_t stream) {
    const float* nf   = (const float*)d_in[0];
    const float* ef   = (const float*)d_in[1];
    const int*   ed   = (const int*)d_in[2];   // edge_domain (scatter dest)
    const int*   er   = (const int*)d_in[3];   // edge_range  (gather src)
    const int*   gid  = (const int*)d_in[4];
    const float* Wm   = (const float*)d_in[5];
    const float* bm   = (const float*)d_in[6];
    const float* Ew   = (const float*)d_in[7];
    const float* Wu0  = (const float*)d_in[8];
    const float* bu0  = (const float*)d_in[9];
    const float* Wu1  = (const float*)d_in[10];
    const float* bu1  = (const float*)d_in[11];
    const float* Wae  = (const float*)d_in[12];
    const float* bae  = (const float*)d_in[13];
    const float* WR   = (const float*)d_in[14];
    const float* bR   = (const float*)d_in[15];
    const float* Wmlp = (const float*)d_in[16];
    const float* bmlp = (const float*)d_in[17];
    const float* Wout = (const float*)d_in[18];
    const float* bout = (const float*)d_in[19];
    float* out = (float*)d_out;

    float* ws   = (float*)d_ws;
    float* h    = ws;                                   // 20000*64 f32
    float* mlpT = ws + 1280000;                         // 64*40000 f32 (transposed mlp)
    float* msg  = ws + 1280000 + 2560000;               // 20000*64 f32
    float* gsum = msg + 1280000;                        // 512*64 f32
    __bf16* ewb = (__bf16*)(gsum + 32768);              // 262144 bf16

    prep_kernel<<<7035, 256, 0, stream>>>(nf, ef, Wm, bm, Ew, h, mlpT, ewb, msg, gsum);

    for (int stepi = 0; stepi < 2; ++stepi) {
        edge_message_mfma<<<(NE + 127) / 128, 256, 0, stream>>>(h, mlpT, ed, er, ewb, msg);
        node_update_kernel<<<NN / 4, 256, 0, stream>>>(msg, stepi ? Wu1 : Wu0,
                                                       stepi ? bu1 : bu0, h);
    }

    embed_readout_kernel<<<NN / 4, 256, 0, stream>>>(h, Wae, bae, WR, bR, gid, gsum);
    final_kernel<<<NB, 64, 0, stream>>>(gsum, Wmlp, bmlp, Wout, bout, out);
}

// Round 8
// 144.895 us; speedup vs baseline: 1.4564x; 1.4564x over previous
//
#include <hip/hip_runtime.h>
#include <math.h>

#define NN 20000   // nodes
#define NE 40000   // edges
#define H 64
#define F_ATOM 62
#define F_BOND 6
#define NB 512     // graphs

typedef _Float16 f16x8 __attribute__((ext_vector_type(8)));
typedef float f32x16 __attribute__((ext_vector_type(16)));

__device__ __forceinline__ float selu_f(float x) {
    const float scale = 1.0507009873554805f;
    const float alpha = 1.6732632423543772f;
    return scale * (x > 0.0f ? x : alpha * (__expf(x) - 1.0f));
}

__device__ __forceinline__ f16x8 splat8h(_Float16 x) {
    union { _Float16 h[2]; unsigned u; } p;
    p.h[0] = x; p.h[1] = x;
    union { unsigned u[4]; f16x8 v; } r;
    r.u[0] = p.u; r.u[1] = p.u; r.u[2] = p.u; r.u[3] = p.u;
    return r.v;
}

// Fused prep, role by blockIdx (256 threads each):
// [0,625)      : mlp2[kkpair][e] = packed f16x2 {relu(ef@Wm+bm)[2p], [2p+1]} via LDS transpose
// [625,5625)   : h = pad(nf) f32 + h_h f16 mirror
// [5625,5753)  : ewb = f16(Ew) in B-fragment-linear order (round-3 verbatim indexing, PASSED)
// [5753,7003)  : zero msg; [7003,7035): zero gsum
__global__ void prep_kernel(const float* __restrict__ nf, const float* __restrict__ ef,
                            const float* __restrict__ Wm, const float* __restrict__ bm,
                            const float* __restrict__ Ew,
                            float* __restrict__ h, _Float16* __restrict__ h_h,
                            unsigned* __restrict__ mlp2, _Float16* __restrict__ ewb,
                            float* __restrict__ msg, float* __restrict__ gsum) {
    const int bid = blockIdx.x;
    const int t = threadIdx.x;
    if (bid < 625) {
        __shared__ float st[64][65];
        const int el = t & 63;
        const int ig = t >> 6;                 // wave id; i = ig*16+p wave-uniform
        const int e = bid * 64 + el;
        const float* efe = ef + e * F_BOND;
        const float e0 = efe[0], e1 = efe[1], e2 = efe[2];
        const float e3 = efe[3], e4 = efe[4], e5 = efe[5];
#pragma unroll
        for (int p = 0; p < 16; ++p) {
            const int i = ig * 16 + p;
            float s = bm[i];
            s = fmaf(e0, Wm[0 * H + i], s);
            s = fmaf(e1, Wm[1 * H + i], s);
            s = fmaf(e2, Wm[2 * H + i], s);
            s = fmaf(e3, Wm[3 * H + i], s);
            s = fmaf(e4, Wm[4 * H + i], s);
            s = fmaf(e5, Wm[5 * H + i], s);
            st[i][el] = fmaxf(s, 0.0f);
        }
        __syncthreads();
        const int p = t >> 3;                  // kk-pair 0..31
        const int ch = t & 7;                  // 8-edge chunk
#pragma unroll
        for (int j = 0; j < 8; ++j) {
            const int e_l = ch * 8 + j;
            union { unsigned u; _Float16 hh[2]; } pk;
            pk.hh[0] = (_Float16)st[2 * p][e_l];
            pk.hh[1] = (_Float16)st[2 * p + 1][e_l];
            mlp2[(size_t)p * NE + bid * 64 + e_l] = pk.u;
        }
    } else if (bid < 5625) {
        int idx = (bid - 625) * 256 + t;
        int n = idx >> 6, c = idx & 63;
        float v = (c < F_ATOM) ? nf[n * F_ATOM + c] : 0.0f;
        h[idx] = v;
        h_h[idx] = (_Float16)v;
    } else if (bid < 5753) {
        int tid = (bid - 5625) * 256 + t;      // 0..32767
        int l = tid & 63;
        int nt = (tid >> 6) & 1;
        int c = tid >> 7;                      // 0..255 = kk*4 + cq
        int kk = c >> 2;
        int jbase = (c & 3) * 16 + (l >> 5) * 8;
        int i = nt * 32 + (l & 31);
        const float* src = Ew + kk * 4096 + i * 64 + jbase;
        _Float16* dst = ewb + tid * 8;
#pragma unroll
        for (int u = 0; u < 8; ++u) dst[u] = (_Float16)src[u];
    } else if (bid < 7003) {
        int idx = (bid - 5753) * 256 + t;
        reinterpret_cast<float4*>(msg)[idx] = make_float4(0.f, 0.f, 0.f, 0.f);
    } else {
        int idx = (bid - 7003) * 256 + t;
        reinterpret_cast<float4*>(gsum)[idx] = make_float4(0.f, 0.f, 0.f, 0.f);
    }
}

// Edge message. Block = 512 thr = 8 waves = 2 M-groups(M=64) x 4 K-groups(16 kk).
// Per kk-step: __syncthreads (drains prev stage) -> stage next slice -> compute.
// K-partials merged via LDS tree reusing dead stage buffers; atomics once.
__global__ __launch_bounds__(512, 4) void edge_message_mfma(
    const _Float16* __restrict__ h_h, const unsigned* __restrict__ mlp2,
    const int* __restrict__ ed, const int* __restrict__ er,
    const _Float16* __restrict__ ewb, float* __restrict__ msg)
{
    __shared__ float4 smem4[4096];        // 64 KB: stage [4q][2buf][8KB] -> merge X|Y
    __shared__ int edom_s[128];

    const int t = threadIdx.x;
    const int w = t >> 6;                 // 0..7
    const int lane = t & 63;
    const int l31 = lane & 31;
    const int hf = lane >> 5;
    const int mg = w >> 2;                // M-group 0..1
    const int q  = w & 3;                 // K-group 0..3 (kk in [16q,16q+16))
    const int eb = blockIdx.x * 128;

    if (t < 128) { int ee = eb + t; edom_s[t] = ed[ee < NE ? ee : NE - 1]; }

    const int eT0 = eb + mg * 64 + l31;   // M-tile 0 row
    const int eT1 = eT0 + 32;             // M-tile 1 row
    const int e0c = eT0 < NE ? eT0 : NE - 1;
    const int e1c = eT1 < NE ? eT1 : NE - 1;
    const int g0 = er[e0c], g1 = er[e1c];

    // hj fragments (f16): j = cq*16 + hf*8 + tt   (proven mapping)
    f16x8 hjA[4], hjB[4];
#pragma unroll
    for (int cq = 0; cq < 4; ++cq) {
        hjA[cq] = *reinterpret_cast<const f16x8*>(h_h + g0 * 64 + cq * 16 + hf * 8);
        hjB[cq] = *reinterpret_cast<const f16x8*>(h_h + g1 * 64 + cq * 16 + hf * 8);
    }

    // mlp pairs: pair pp covers kk {q*16+2pp, q*16+2pp+1}
    unsigned mv0[8], mv1[8];
#pragma unroll
    for (int pp = 0; pp < 4; ++pp) {
        mv0[pp] = mlp2[(size_t)(q * 8 + pp) * NE + e0c];
        mv1[pp] = mlp2[(size_t)(q * 8 + pp) * NE + e1c];
    }

    char* sm = reinterpret_cast<char*>(smem4);
    // stage half-slice: wave (mg,q) copies bytes [mg*4K, mg*4K+4K) of slice kk=q*16+s
    auto stage = [&](int s) {
        const char* gs = reinterpret_cast<const char*>(ewb) +
                         ((size_t)(q * 16 + s) << 13) + (mg << 12) + lane * 16;
        char* lb = sm + ((q * 2 + (s & 1)) << 13) + (mg << 12) + lane * 16;
#pragma unroll
        for (int r = 0; r < 4; ++r) {
            __builtin_amdgcn_global_load_lds(
                (const __attribute__((address_space(1))) void*)(gs + r * 1024),
                (__attribute__((address_space(3))) void*)(lb + r * 1024),
                16, 0, 0);
        }
    };

    f32x16 a00, a01, a10, a11;
#pragma unroll
    for (int i = 0; i < 16; ++i) { a00[i] = 0.f; a01[i] = 0.f; a10[i] = 0.f; a11[i] = 0.f; }

    stage(0);

#pragma unroll
    for (int s = 0; s < 16; ++s) {
        __syncthreads();                  // drains stage(s) DMA (vmcnt0) + barrier
        if (s == 4) {                     // second mval batch, 4 steps ahead of use
#pragma unroll
            for (int pp = 4; pp < 8; ++pp) {
                mv0[pp] = mlp2[(size_t)(q * 8 + pp) * NE + e0c];
                mv1[pp] = mlp2[(size_t)(q * 8 + pp) * NE + e1c];
            }
        }
        if (s < 15) stage(s + 1);         // safe: all compute(s-1) reads completed
        const char* buf = sm + ((q * 2 + (s & 1)) << 13);
        union { unsigned u; _Float16 hh[2]; } ua, ub;
        ua.u = mv0[s >> 1]; ub.u = mv1[s >> 1];
        f16x8 sA = splat8h(ua.hh[s & 1]);
        f16x8 sB = splat8h(ub.hh[s & 1]);
#pragma unroll
        for (int cq = 0; cq < 4; ++cq) {
            f16x8 b0 = *reinterpret_cast<const f16x8*>(buf + (cq * 2 + 0) * 1024 + lane * 16);
            f16x8 b1 = *reinterpret_cast<const f16x8*>(buf + (cq * 2 + 1) * 1024 + lane * 16);
            f16x8 aA = sA * hjA[cq];
            f16x8 aB = sB * hjB[cq];
            a00 = __builtin_amdgcn_mfma_f32_32x32x16_f16(aA, b0, a00, 0, 0, 0);
            a01 = __builtin_amdgcn_mfma_f32_32x32x16_f16(aA, b1, a01, 0, 0, 0);
            a10 = __builtin_amdgcn_mfma_f32_32x32x16_f16(aB, b0, a10, 0, 0, 0);
            a11 = __builtin_amdgcn_mfma_f32_32x32x16_f16(aB, b1, a11, 0, 0, 0);
        }
    }

    // ---- K-partial merge tree in LDS (stage area now dead) ----
    // C/D row formula (proven): m = (r&3) + 8*(r>>2) + 4*hf
    float* X = reinterpret_cast<float*>(smem4);        // 32 KB: [2 mg][64 e][64 c]
    float* Y = X + 8192;                               // 32 KB
    __syncthreads();
    if (q >= 2) {                         // q2 -> X, q3 -> Y
        float* M = (q == 2) ? X : Y;
#pragma unroll
        for (int r = 0; r < 16; ++r) {
            const int m = (r & 3) + 8 * (r >> 2) + 4 * hf;
            M[mg * 4096 + m * 64 + l31]             = a00[r];
            M[mg * 4096 + m * 64 + 32 + l31]        = a01[r];
            M[mg * 4096 + (32 + m) * 64 + l31]      = a10[r];
            M[mg * 4096 + (32 + m) * 64 + 32 + l31] = a11[r];
        }
    }
    __syncthreads();
    if (q == 0) {
#pragma unroll
        for (int r = 0; r < 16; ++r) {
            const int m = (r & 3) + 8 * (r >> 2) + 4 * hf;
            a00[r] += X[mg * 4096 + m * 64 + l31];
            a01[r] += X[mg * 4096 + m * 64 + 32 + l31];
            a10[r] += X[mg * 4096 + (32 + m) * 64 + l31];
            a11[r] += X[mg * 4096 + (32 + m) * 64 + 32 + l31];
        }
    } else if (q == 1) {
#pragma unroll
        for (int r = 0; r < 16; ++r) {
            const int m = (r & 3) + 8 * (r >> 2) + 4 * hf;
            a00[r] += Y[mg * 4096 + m * 64 + l31];
            a01[r] += Y[mg * 4096 + m * 64 + 32 + l31];
            a10[r] += Y[mg * 4096 + (32 + m) * 64 + l31];
            a11[r] += Y[mg * 4096 + (32 + m) * 64 + 32 + l31];
        }
    }
    __syncthreads();
    if (q == 1) {                         // write (q1+q3) into X
#pragma unroll
        for (int r = 0; r < 16; ++r) {
            const int m = (r & 3) + 8 * (r >> 2) + 4 * hf;
            X[mg * 4096 + m * 64 + l31]             = a00[r];
            X[mg * 4096 + m * 64 + 32 + l31]        = a01[r];
            X[mg * 4096 + (32 + m) * 64 + l31]      = a10[r];
            X[mg * 4096 + (32 + m) * 64 + 32 + l31] = a11[r];
        }
    }
    __syncthreads();
    if (q == 0) {                         // full sum -> X
#pragma unroll
        for (int r = 0; r < 16; ++r) {
            const int m = (r & 3) + 8 * (r >> 2) + 4 * hf;
            X[mg * 4096 + m * 64 + l31]             = a00[r] + X[mg * 4096 + m * 64 + l31];
            X[mg * 4096 + m * 64 + 32 + l31]        = a01[r] + X[mg * 4096 + m * 64 + 32 + l31];
            X[mg * 4096 + (32 + m) * 64 + l31]      = a10[r] + X[mg * 4096 + (32 + m) * 64 + l31];
            X[mg * 4096 + (32 + m) * 64 + 32 + l31] = a11[r] + X[mg * 4096 + (32 + m) * 64 + 32 + l31];
        }
    }
    __syncthreads();
    // scatter: wave w handles edges [w*16, w*16+16), lane = column
#pragma unroll
    for (int i = 0; i < 16; ++i) {
        const int e_loc = w * 16 + i;
        const int e = eb + e_loc;
        if (e < NE) {
            const int dom = edom_s[e_loc];
            atomicAdd(&msg[dom * 64 + lane], X[e_loc * 64 + lane]);
        }
    }
}

// h[n,i] = selu(msg[n] @ Wu + bu[i] + h[n,i]); h_h mirror; zeroes msg (round-3 verbatim + mirror)
__global__ void node_update_kernel(float* __restrict__ msg, const float* __restrict__ Wu,
                                   const float* __restrict__ bu, float* __restrict__ h,
                                   _Float16* __restrict__ h_h) {
    __shared__ float ms[4][68];
    int t = threadIdx.x;
    int nb = blockIdx.x * 4;
    int ln = t >> 6, i = t & 63;
    int o = (nb + ln) * H + i;
    ms[ln][i] = msg[o];
    msg[o] = 0.0f;                       // ready for next edge_message / replay
    __syncthreads();
    float s = bu[i];
#pragma unroll
    for (int k = 0; k < H; ++k) s = fmaf(ms[ln][k], Wu[k * H + i], s);
    float v = selu_f(s + h[o]);
    h[o] = v;
    h_h[o] = (_Float16)v;
}

// fused: ae = h@Wae+bae; aa = selu(ae@WR+bR); atomicAdd gsum[gid[n]]   (round-3 verbatim)
__global__ void embed_readout_kernel(const float* __restrict__ h, const float* __restrict__ Wae,
                                     const float* __restrict__ bae, const float* __restrict__ WR,
                                     const float* __restrict__ bR, const int* __restrict__ gid,
                                     float* __restrict__ gsum) {
    __shared__ float hs[4][68];
    __shared__ float as_[4][68];
    int t = threadIdx.x;
    int nb = blockIdx.x * 4;
    int ln = t >> 6, i = t & 63;
    hs[ln][i] = h[(nb + ln) * H + i];
    __syncthreads();
    float s = bae[i];
#pragma unroll
    for (int k = 0; k < H; ++k) s = fmaf(hs[ln][k], Wae[k * H + i], s);
    as_[ln][i] = s;
    __syncthreads();
    float s2 = bR[i];
#pragma unroll
    for (int k = 0; k < H; ++k) s2 = fmaf(as_[ln][k], WR[k * H + i], s2);
    atomicAdd(&gsum[gid[nb + ln] * H + i], selu_f(s2));
}

// per graph: ge = tanh(gsum); mo = relu(ge @ Wmlp + bmlp); out = mo @ Wout + bout (round-1 verbatim)
__global__ void final_kernel(const float* __restrict__ gsum, const float* __restrict__ Wmlp,
                             const float* __restrict__ bmlp, const float* __restrict__ Wout,
                             const float* __restrict__ bout, float* __restrict__ out) {
    __shared__ float ge[64];
    int g = blockIdx.x, i = threadIdx.x;
    ge[i] = tanhf(gsum[g * H + i]);
    __syncthreads();
    float s = bmlp[i];
#pragma unroll
    for (int k = 0; k < H; ++k) s = fmaf(ge[k], Wmlp[k * H + i], s);
    float mo = fmaxf(s, 0.0f) * Wout[i];
#pragma unroll
    for (int off = 32; off > 0; off >>= 1) mo += __shfl_down(mo, off);
    if (i == 0) out[g] = mo + bout[0];
}

extern "C" void kernel_launch(void* const* d_in, const int* in_sizes, int n_in,
                              void* d_out, int out_size, void* d_ws, size_t ws_size,
                              hipStream_t stream) {
    const float* nf   = (const float*)d_in[0];
    const float* ef   = (const float*)d_in[1];
    const int*   ed   = (const int*)d_in[2];   // edge_domain (scatter dest)
    const int*   er   = (const int*)d_in[3];   // edge_range  (gather src)
    const int*   gid  = (const int*)d_in[4];
    const float* Wm   = (const float*)d_in[5];
    const float* bm   = (const float*)d_in[6];
    const float* Ew   = (const float*)d_in[7];
    const float* Wu0  = (const float*)d_in[8];
    const float* bu0  = (const float*)d_in[9];
    const float* Wu1  = (const float*)d_in[10];
    const float* bu1  = (const float*)d_in[11];
    const float* Wae  = (const float*)d_in[12];
    const float* bae  = (const float*)d_in[13];
    const float* WR   = (const float*)d_in[14];
    const float* bR   = (const float*)d_in[15];
    const float* Wmlp = (const float*)d_in[16];
    const float* bmlp = (const float*)d_in[17];
    const float* Wout = (const float*)d_in[18];
    const float* bout = (const float*)d_in[19];
    float* out = (float*)d_out;

    float* ws = (float*)d_ws;
    float*    h    = ws;                              // 1,280,000 f32
    float*    msg  = ws + 1280000;                    // 1,280,000 f32
    float*    gsum = ws + 2560000;                    // 32,768 f32
    unsigned* mlp2 = (unsigned*)(ws + 2592768);       // 32*40000 u32 (f16x2 pairs)
    _Float16* h_h  = (_Float16*)(ws + 3872768);       // 1,280,000 f16
    _Float16* ewb  = (_Float16*)(ws + 4512768);       // 262,144 f16

    prep_kernel<<<7035, 256, 0, stream>>>(nf, ef, Wm, bm, Ew, h, h_h, mlp2, ewb, msg, gsum);

    for (int stepi = 0; stepi < 2; ++stepi) {
        edge_message_mfma<<<313, 512, 0, stream>>>(h_h, mlp2, ed, er, ewb, msg);
        node_update_kernel<<<NN / 4, 256, 0, stream>>>(msg, stepi ? Wu1 : Wu0,
                                                       stepi ? bu1 : bu0, h, h_h);
    }

    embed_readout_kernel<<<NN / 4, 256, 0, stream>>>(h, Wae, bae, WR, bR, gid, gsum);
    final_kernel<<<NB, 64, 0, stream>>>(gsum, Wmlp, bmlp, Wout, bout, out);
}

// Round 9
// 133.326 us; speedup vs baseline: 1.5828x; 1.0868x over previous
//
#include <hip/hip_runtime.h>
#include <math.h>

#define NN 20000   // nodes
#define NE 40000   // edges
#define H 64
#define F_ATOM 62
#define F_BOND 6
#define NB 512     // graphs

typedef _Float16 f16x8 __attribute__((ext_vector_type(8)));
typedef float f32x16 __attribute__((ext_vector_type(16)));

__device__ __forceinline__ float selu_f(float x) {
    const float scale = 1.0507009873554805f;
    const float alpha = 1.6732632423543772f;
    return scale * (x > 0.0f ? x : alpha * (__expf(x) - 1.0f));
}

__device__ __forceinline__ f16x8 splat8h(_Float16 x) {
    union { _Float16 h[2]; unsigned u; } p;
    p.h[0] = x; p.h[1] = x;
    union { unsigned u[4]; f16x8 v; } r;
    r.u[0] = p.u; r.u[1] = p.u; r.u[2] = p.u; r.u[3] = p.u;
    return r.v;
}

// Fused prep, role by blockIdx (256 threads each)  — round-8 verbatim (PASSED):
// [0,625)      : mlp2[kkpair][e] = packed f16x2 {relu(ef@Wm+bm)[2p], [2p+1]} via LDS transpose
// [625,5625)   : h = pad(nf) f32 + h_h f16 mirror
// [5625,5753)  : ewb = f16(Ew) in B-fragment-linear order
// [5753,7003)  : zero msg; [7003,7035): zero gsum
__global__ void prep_kernel(const float* __restrict__ nf, const float* __restrict__ ef,
                            const float* __restrict__ Wm, const float* __restrict__ bm,
                            const float* __restrict__ Ew,
                            float* __restrict__ h, _Float16* __restrict__ h_h,
                            unsigned* __restrict__ mlp2, _Float16* __restrict__ ewb,
                            float* __restrict__ msg, float* __restrict__ gsum) {
    const int bid = blockIdx.x;
    const int t = threadIdx.x;
    if (bid < 625) {
        __shared__ float st[64][65];
        const int el = t & 63;
        const int ig = t >> 6;                 // wave id; i = ig*16+p wave-uniform
        const int e = bid * 64 + el;
        const float* efe = ef + e * F_BOND;
        const float e0 = efe[0], e1 = efe[1], e2 = efe[2];
        const float e3 = efe[3], e4 = efe[4], e5 = efe[5];
#pragma unroll
        for (int p = 0; p < 16; ++p) {
            const int i = ig * 16 + p;
            float s = bm[i];
            s = fmaf(e0, Wm[0 * H + i], s);
            s = fmaf(e1, Wm[1 * H + i], s);
            s = fmaf(e2, Wm[2 * H + i], s);
            s = fmaf(e3, Wm[3 * H + i], s);
            s = fmaf(e4, Wm[4 * H + i], s);
            s = fmaf(e5, Wm[5 * H + i], s);
            st[i][el] = fmaxf(s, 0.0f);
        }
        __syncthreads();
        const int p = t >> 3;                  // kk-pair 0..31
        const int ch = t & 7;                  // 8-edge chunk
#pragma unroll
        for (int j = 0; j < 8; ++j) {
            const int e_l = ch * 8 + j;
            union { unsigned u; _Float16 hh[2]; } pk;
            pk.hh[0] = (_Float16)st[2 * p][e_l];
            pk.hh[1] = (_Float16)st[2 * p + 1][e_l];
            mlp2[(size_t)p * NE + bid * 64 + e_l] = pk.u;
        }
    } else if (bid < 5625) {
        int idx = (bid - 625) * 256 + t;
        int n = idx >> 6, c = idx & 63;
        float v = (c < F_ATOM) ? nf[n * F_ATOM + c] : 0.0f;
        h[idx] = v;
        h_h[idx] = (_Float16)v;
    } else if (bid < 5753) {
        int tid = (bid - 5625) * 256 + t;      // 0..32767
        int l = tid & 63;
        int nt = (tid >> 6) & 1;
        int c = tid >> 7;                      // 0..255 = kk*4 + cq
        int kk = c >> 2;
        int jbase = (c & 3) * 16 + (l >> 5) * 8;
        int i = nt * 32 + (l & 31);
        const float* src = Ew + kk * 4096 + i * 64 + jbase;
        _Float16* dst = ewb + tid * 8;
#pragma unroll
        for (int u = 0; u < 8; ++u) dst[u] = (_Float16)src[u];
    } else if (bid < 7003) {
        int idx = (bid - 5753) * 256 + t;
        reinterpret_cast<float4*>(msg)[idx] = make_float4(0.f, 0.f, 0.f, 0.f);
    } else {
        int idx = (bid - 7003) * 256 + t;
        reinterpret_cast<float4*>(gsum)[idx] = make_float4(0.f, 0.f, 0.f, 0.f);
    }
}

// Edge message. Block = 256 thr = 4 waves = 2 M-groups(32 edges) x 2 K-groups(32 kk).
// Grid = 625 (40000/64 exact, no tail). 33 KB LDS + launch_bounds(256,4) -> 4 blocks/CU:
// independent barrier groups interleave, hiding each group's stage latency.
// Per kk-step: __syncthreads (drains prev DMA) -> stage next 8KB slice -> compute.
// K-partials merged in LDS (stage area reused); atomics once (10 MB).
// A-build / B byte-layout / C/D row formula: round-8 verbatim (PASSED, 6.1e-5).
__global__ __launch_bounds__(256, 4) void edge_message_mfma(
    const _Float16* __restrict__ h_h, const unsigned* __restrict__ mlp2,
    const int* __restrict__ ed, const int* __restrict__ er,
    const _Float16* __restrict__ ewb, float* __restrict__ msg)
{
    __shared__ float4 smem4[2048];        // 32 KB: stage [2 kg][2 buf][8 KB]; merge reuses 16 KB
    __shared__ int edom_s[64];

    const int t = threadIdx.x;
    const int w = t >> 6;                 // 0..3
    const int lane = t & 63;
    const int l31 = lane & 31;
    const int hf = lane >> 5;
    const int mg = w & 1;                 // M-group 0..1 (which 32-edge tile)
    const int kg = w >> 1;                // K-group 0..1 (kk in [kg*32, kg*32+32))
    const int eb = blockIdx.x * 64;

    if (t < 64) edom_s[t] = ed[eb + t];

    const int e = eb + mg * 32 + l31;     // exact: 625*64 == NE
    const int g0 = er[e];

    // hj fragments (f16): j = cq*16 + hf*8 + tt   (proven mapping)
    f16x8 hj[4];
#pragma unroll
    for (int cq = 0; cq < 4; ++cq)
        hj[cq] = *reinterpret_cast<const f16x8*>(h_h + g0 * 64 + cq * 16 + hf * 8);

    // mlp pairs: kg covers pairs [kg*16, kg*16+16); pair pp -> kk {2pp, 2pp+1}
    unsigned mv[16];
#pragma unroll
    for (int pp = 0; pp < 16; ++pp)
        mv[pp] = mlp2[(size_t)(kg * 16 + pp) * NE + e];

    char* sm = reinterpret_cast<char*>(smem4);
    // stage 8KB slice kk = kg*32+s into buf (kg*2 + (s&1)); mg-waves split 4KB halves
    auto stage = [&](int s) {
        const char* gs = reinterpret_cast<const char*>(ewb) +
                         ((size_t)(kg * 32 + s) << 13) + (mg << 12) + lane * 16;
        char* lb = sm + ((size_t)(kg * 2 + (s & 1)) << 13) + (mg << 12) + lane * 16;
#pragma unroll
        for (int r = 0; r < 4; ++r) {
            __builtin_amdgcn_global_load_lds(
                (const __attribute__((address_space(1))) void*)(gs + r * 1024),
                (__attribute__((address_space(3))) void*)(lb + r * 1024),
                16, 0, 0);
        }
    };

    f32x16 acc0, acc1;
#pragma unroll
    for (int i = 0; i < 16; ++i) { acc0[i] = 0.f; acc1[i] = 0.f; }

    stage(0);

#pragma unroll
    for (int s = 0; s < 32; ++s) {
        __syncthreads();                  // stage(s) DMA drained (own vmcnt) + barrier
        if (s < 31) stage(s + 1);         // lands during compute(s)
        const char* buf = sm + ((size_t)(kg * 2 + (s & 1)) << 13);
        union { unsigned u; _Float16 hh[2]; } ua;
        ua.u = mv[s >> 1];
        f16x8 sA = splat8h(ua.hh[s & 1]);
#pragma unroll
        for (int cq = 0; cq < 4; ++cq) {
            f16x8 b0 = *reinterpret_cast<const f16x8*>(buf + (cq * 2 + 0) * 1024 + lane * 16);
            f16x8 b1 = *reinterpret_cast<const f16x8*>(buf + (cq * 2 + 1) * 1024 + lane * 16);
            f16x8 aA = sA * hj[cq];
            acc0 = __builtin_amdgcn_mfma_f32_32x32x16_f16(aA, b0, acc0, 0, 0, 0);
            acc1 = __builtin_amdgcn_mfma_f32_32x32x16_f16(aA, b1, acc1, 0, 0, 0);
        }
    }

    // ---- K-partial merge in LDS (stage area now dead) ----
    // C/D row formula (proven): m = (r&3) + 8*(r>>2) + 4*hf
    float* X = reinterpret_cast<float*>(smem4);        // 16 KB: [64 e_loc][64 col]
    __syncthreads();                      // all reads of stage LDS complete
    if (kg == 1) {
#pragma unroll
        for (int r = 0; r < 16; ++r) {
            const int m = (r & 3) + 8 * (r >> 2) + 4 * hf;
            X[(mg * 32 + m) * 64 + l31]      = acc0[r];
            X[(mg * 32 + m) * 64 + 32 + l31] = acc1[r];
        }
    }
    __syncthreads();
    if (kg == 0) {
#pragma unroll
        for (int r = 0; r < 16; ++r) {
            const int m = (r & 3) + 8 * (r >> 2) + 4 * hf;
            const int dom = edom_s[mg * 32 + m];
            atomicAdd(&msg[dom * 64 + l31],      acc0[r] + X[(mg * 32 + m) * 64 + l31]);
            atomicAdd(&msg[dom * 64 + 32 + l31], acc1[r] + X[(mg * 32 + m) * 64 + 32 + l31]);
        }
    }
}

// h[n,i] = selu(msg[n] @ Wu + bu[i] + h[n,i]); h_h mirror; zeroes msg (round-8 verbatim)
__global__ void node_update_kernel(float* __restrict__ msg, const float* __restrict__ Wu,
                                   const float* __restrict__ bu, float* __restrict__ h,
                                   _Float16* __restrict__ h_h) {
    __shared__ float ms[4][68];
    int t = threadIdx.x;
    int nb = blockIdx.x * 4;
    int ln = t >> 6, i = t & 63;
    int o = (nb + ln) * H + i;
    ms[ln][i] = msg[o];
    msg[o] = 0.0f;                       // ready for next edge_message / replay
    __syncthreads();
    float s = bu[i];
#pragma unroll
    for (int k = 0; k < H; ++k) s = fmaf(ms[ln][k], Wu[k * H + i], s);
    float v = selu_f(s + h[o]);
    h[o] = v;
    h_h[o] = (_Float16)v;
}

// fused: ae = h@Wae+bae; aa = selu(ae@WR+bR); atomicAdd gsum[gid[n]]   (round-8 verbatim)
__global__ void embed_readout_kernel(const float* __restrict__ h, const float* __restrict__ Wae,
                                     const float* __restrict__ bae, const float* __restrict__ WR,
                                     const float* __restrict__ bR, const int* __restrict__ gid,
                                     float* __restrict__ gsum) {
    __shared__ float hs[4][68];
    __shared__ float as_[4][68];
    int t = threadIdx.x;
    int nb = blockIdx.x * 4;
    int ln = t >> 6, i = t & 63;
    hs[ln][i] = h[(nb + ln) * H + i];
    __syncthreads();
    float s = bae[i];
#pragma unroll
    for (int k = 0; k < H; ++k) s = fmaf(hs[ln][k], Wae[k * H + i], s);
    as_[ln][i] = s;
    __syncthreads();
    float s2 = bR[i];
#pragma unroll
    for (int k = 0; k < H; ++k) s2 = fmaf(as_[ln][k], WR[k * H + i], s2);
    atomicAdd(&gsum[gid[nb + ln] * H + i], selu_f(s2));
}

// per graph: ge = tanh(gsum); mo = relu(ge @ Wmlp + bmlp); out = mo @ Wout + bout (round-8 verbatim)
__global__ void final_kernel(const float* __restrict__ gsum, const float* __restrict__ Wmlp,
                             const float* __restrict__ bmlp, const float* __restrict__ Wout,
                             const float* __restrict__ bout, float* __restrict__ out) {
    __shared__ float ge[64];
    int g = blockIdx.x, i = threadIdx.x;
    ge[i] = tanhf(gsum[g * H + i]);
    __syncthreads();
    float s = bmlp[i];
#pragma unroll
    for (int k = 0; k < H; ++k) s = fmaf(ge[k], Wmlp[k * H + i], s);
    float mo = fmaxf(s, 0.0f) * Wout[i];
#pragma unroll
    for (int off = 32; off > 0; off >>= 1) mo += __shfl_down(mo, off);
    if (i == 0) out[g] = mo + bout[0];
}

extern "C" void kernel_launch(void* const* d_in, const int* in_sizes, int n_in,
                              void* d_out, int out_size, void* d_ws, size_t ws_size,
                              hipStream_t stream) {
    const float* nf   = (const float*)d_in[0];
    const float* ef   = (const float*)d_in[1];
    const int*   ed   = (const int*)d_in[2];   // edge_domain (scatter dest)
    const int*   er   = (const int*)d_in[3];   // edge_range  (gather src)
    const int*   gid  = (const int*)d_in[4];
    const float* Wm   = (const float*)d_in[5];
    const float* bm   = (const float*)d_in[6];
    const float* Ew   = (const float*)d_in[7];
    const float* Wu0  = (const float*)d_in[8];
    const float* bu0  = (const float*)d_in[9];
    const float* Wu1  = (const float*)d_in[10];
    const float* bu1  = (const float*)d_in[11];
    const float* Wae  = (const float*)d_in[12];
    const float* bae  = (const float*)d_in[13];
    const float* WR   = (const float*)d_in[14];
    const float* bR   = (const float*)d_in[15];
    const float* Wmlp = (const float*)d_in[16];
    const float* bmlp = (const float*)d_in[17];
    const float* Wout = (const float*)d_in[18];
    const float* bout = (const float*)d_in[19];
    float* out = (float*)d_out;

    float* ws = (float*)d_ws;
    float*    h    = ws;                              // 1,280,000 f32
    float*    msg  = ws + 1280000;                    // 1,280,000 f32
    float*    gsum = ws + 2560000;                    // 32,768 f32
    unsigned* mlp2 = (unsigned*)(ws + 2592768);       // 32*40000 u32 (f16x2 pairs)
    _Float16* h_h  = (_Float16*)(ws + 3872768);       // 1,280,000 f16
    _Float16* ewb  = (_Float16*)(ws + 4512768);       // 262,144 f16

    prep_kernel<<<7035, 256, 0, stream>>>(nf, ef, Wm, bm, Ew, h, h_h, mlp2, ewb, msg, gsum);

    for (int stepi = 0; stepi < 2; ++stepi) {
        edge_message_mfma<<<625, 256, 0, stream>>>(h_h, mlp2, ed, er, ewb, msg);
        node_update_kernel<<<NN / 4, 256, 0, stream>>>(msg, stepi ? Wu1 : Wu0,
                                                       stepi ? bu1 : bu0, h, h_h);
    }

    embed_readout_kernel<<<NN / 4, 256, 0, stream>>>(h, Wae, bae, WR, bR, gid, gsum);
    final_kernel<<<NB, 64, 0, stream>>>(gsum, Wmlp, bmlp, Wout, bout, out);
}